// Round 2
// baseline (326.181 us; speedup 1.0000x reference)
//
#include <hip/hip_runtime.h>
#include <hip/hip_bf16.h>

// TripletLoss N=8192, D=128. Round 2: symmetry-halved fused kernel.
// dist(i,j)=dist(j,i), and both exp(-d) (neg softmax) and exp(d-30) (pos
// softmax, shift-stabilized) are row-independent values -> compute each
// unordered pair once (j>i), scatter to row i (registers) and row j (LDS
// column sums), accumulate rows via global float atomics.

typedef __bf16 bf16x8 __attribute__((ext_vector_type(8)));
typedef float f32x4 __attribute__((ext_vector_type(4)));

#define NROWS 8192
#define DIM 128
#define TILE 64
#define NT (NROWS / TILE)   // 128 tiles per side
#define LDS_STRIDE 136      // 128 + 8 bf16 pad
#define MARGIN_F 0.3f
#define POS_SHIFT 30.0f

// rowacc[row][4] = {neg_l, neg_s, pos_l, pos_s}

// ---------------- kernel 1: bf16 cast + row norms + zero accumulators ----
__global__ __launch_bounds__(256) void prep_kernel(const float* __restrict__ F,
                                                   __hip_bfloat16* __restrict__ Fb,
                                                   float* __restrict__ x2,
                                                   float* __restrict__ rowacc,
                                                   float* __restrict__ gstat) {
    const int tid = threadIdx.x;
    const int wave = tid >> 6, lane = tid & 63;
    const int row = blockIdx.x * 4 + wave;
    float2 f = ((const float2*)(F + (size_t)row * DIM))[lane];
    ((__hip_bfloat162*)(Fb + (size_t)row * DIM))[lane] = __float22bfloat162_rn(f);
    float ss = f.x * f.x + f.y * f.y;
#pragma unroll
    for (int m = 32; m > 0; m >>= 1) ss += __shfl_xor(ss, m, 64);
    if (lane == 0) x2[row] = ss;
    const int g = blockIdx.x * 256 + tid;
    if (g < NROWS * 4) rowacc[g] = 0.f;
    if (g < 2) gstat[g] = 0.f;
}

// ---------------- kernel 2: triangular fused GEMM + mining ----------------
// grid (NT, NT); block ti=bx, tj=by handles 64x64 tile; tj<ti exits.
__global__ __launch_bounds__(256, 4) void pairs_kernel(
        const __hip_bfloat16* __restrict__ Fb,
        const float* __restrict__ x2,
        const int* __restrict__ labels,
        float* __restrict__ rowacc) {
    const int ti = blockIdx.x, tj = blockIdx.y;
    if (tj < ti) return;

    __shared__ __hip_bfloat16 sB[TILE * LDS_STRIDE];
    __shared__ int sLab[TILE];
    __shared__ float sX2[TILE];
    __shared__ float sIacc[TILE][4];
    __shared__ float sJacc[TILE][4];

    const int tid = threadIdx.x;
    const int wave = tid >> 6, lane = tid & 63;
    const int quad = lane >> 4, lm = lane & 15;
    const int ibase = ti * TILE, jbase = tj * TILE;
    const int rbase = ibase + wave * 16;

    ((float*)sIacc)[tid] = 0.f;   // 64*4 = 256 floats each
    ((float*)sJacc)[tid] = 0.f;

    // stage B tile: 64 rows x 256B, 16B chunks, coalesced
#pragma unroll
    for (int s = 0; s < 4; ++s) {
        int c = tid + s * 256;
        int jr = c >> 4, ck = c & 15;
        *(bf16x8*)(sB + jr * LDS_STRIDE + ck * 8) =
            *(const bf16x8*)(Fb + (size_t)(jbase + jr) * DIM + ck * 8);
    }
    if (tid < TILE) { sLab[tid] = labels[jbase + tid]; sX2[tid] = x2[jbase + tid]; }

    // A fragments: A[m=lane&15][k=quad*8+j] (16 rows x K=128 in regs)
    bf16x8 a[4];
#pragma unroll
    for (int kc = 0; kc < 4; ++kc)
        a[kc] = *(const bf16x8*)(Fb + (size_t)(rbase + lm) * DIM + kc * 32 + quad * 8);

    // C/D: col=lane&15, row=quad*4+r
    int ig[4]; float x2i[4]; int labi[4];
#pragma unroll
    for (int r = 0; r < 4; ++r) {
        ig[r] = rbase + quad * 4 + r;
        x2i[r] = x2[ig[r]];
        labi[r] = labels[ig[r]];
    }

    float inl[4] = {0,0,0,0}, ins[4] = {0,0,0,0};
    float ipl[4] = {0,0,0,0}, ips[4] = {0,0,0,0};

    __syncthreads();

#pragma unroll
    for (int jt = 0; jt < 4; ++jt) {
        const int jl = jt * 16 + lm;
        const __hip_bfloat16* bp = sB + jl * LDS_STRIDE + quad * 8;
        f32x4 acc = {0.f, 0.f, 0.f, 0.f};
#pragma unroll
        for (int kc = 0; kc < 4; ++kc) {
            bf16x8 b = *(const bf16x8*)(bp + kc * 32);
            acc = __builtin_amdgcn_mfma_f32_16x16x32_bf16(a[kc], b, acc, 0, 0, 0);
        }
        const int labj = sLab[jl];
        const float x2j = sX2[jl];
        const int jglob = jbase + jl;
        float cnl = 0.f, cns = 0.f, cpl = 0.f, cps = 0.f;
#pragma unroll
        for (int r = 0; r < 4; ++r) {
            float d2 = fmaxf(x2i[r] + x2j - 2.0f * acc[r], 1e-8f);
            float dist = sqrtf(d2);
            bool pred = jglob > ig[r];        // each unordered pair once
            bool same = (labj == labi[r]);
            float ne = __expf(-dist);
            float mne = (pred && !same) ? ne : 0.f;
            inl[r] += mne; ins[r] = fmaf(mne, dist, ins[r]);
            cnl += mne;    cns = fmaf(mne, dist, cns);
            if (pred && same) {               // rare (~0.2%)
                float pe = __expf(dist - POS_SHIFT);
                ipl[r] += pe; ips[r] = fmaf(pe, dist, ips[r]);
                cpl += pe;    cps = fmaf(pe, dist, cps);
            }
        }
        // column (j-side) sums: 4-way lane collisions per address, LDS atomics
        atomicAdd(&sJacc[jl][0], cnl);
        atomicAdd(&sJacc[jl][1], cns);
        if (cpl != 0.f) { atomicAdd(&sJacc[jl][2], cpl); atomicAdd(&sJacc[jl][3], cps); }
    }

    // flush i-side registers to LDS (16-way lm collisions, once per block)
#pragma unroll
    for (int r = 0; r < 4; ++r) {
        const int ir = wave * 16 + quad * 4 + r;
        atomicAdd(&sIacc[ir][0], inl[r]);
        atomicAdd(&sIacc[ir][1], ins[r]);
        if (ipl[r] != 0.f) { atomicAdd(&sIacc[ir][2], ipl[r]); atomicAdd(&sIacc[ir][3], ips[r]); }
    }
    __syncthreads();

    // flush LDS tiles to global row accumulators
    if (tid < TILE) {
#pragma unroll
        for (int q = 0; q < 4; ++q)
            unsafeAtomicAdd(&rowacc[(size_t)(ibase + tid) * 4 + q], sIacc[tid][q]);
    } else if (tid < 2 * TILE) {
        const int t = tid - TILE;
#pragma unroll
        for (int q = 0; q < 4; ++q)
            unsafeAtomicAdd(&rowacc[(size_t)(jbase + t) * 4 + q], sJacc[t][q]);
    }
}

// ---------------- kernel 3: per-row loss, multi-block reduce ----------------
__global__ __launch_bounds__(256) void finalize_kernel(const float* __restrict__ rowacc,
                                                       float* __restrict__ gstat) {
    const int row = blockIdx.x * 256 + threadIdx.x;
    const float4 p = ((const float4*)rowacc)[row];   // {neg_l, neg_s, pos_l, pos_s}
    float sum = 0.f, cnt = 0.f;
    if (p.z > 0.f && p.x > 0.f) {
        float wp = p.w / p.z;
        float wn = p.y / p.x;
        float xx = wp - wn + MARGIN_F;
        sum = fmaxf(xx, 0.f) + log1pf(__expf(-fabsf(xx)));   // stable softplus
        cnt = 1.f;
    }
#pragma unroll
    for (int m = 32; m > 0; m >>= 1) {
        sum += __shfl_xor(sum, m, 64);
        cnt += __shfl_xor(cnt, m, 64);
    }
    __shared__ float sS[4], sC[4];
    const int wave = threadIdx.x >> 6, lane = threadIdx.x & 63;
    if (lane == 0) { sS[wave] = sum; sC[wave] = cnt; }
    __syncthreads();
    if (threadIdx.x == 0) {
        unsafeAtomicAdd(&gstat[0], sS[0] + sS[1] + sS[2] + sS[3]);
        unsafeAtomicAdd(&gstat[1], sC[0] + sC[1] + sC[2] + sC[3]);
    }
}

__global__ void div_kernel(const float* __restrict__ gstat, float* __restrict__ out) {
    out[0] = gstat[0] / fmaxf(gstat[1], 1.0f);
}

extern "C" void kernel_launch(void* const* d_in, const int* in_sizes, int n_in,
                              void* d_out, int out_size, void* d_ws, size_t ws_size,
                              hipStream_t stream) {
    const float* F = (const float*)d_in[0];
    const int* labels = (const int*)d_in[1];
    float* out = (float*)d_out;

    char* ws = (char*)d_ws;
    __hip_bfloat16* Fb = (__hip_bfloat16*)ws;                        // 2 MB
    float* x2 = (float*)(ws + (size_t)NROWS * DIM * 2);              // 32 KB
    float* rowacc = (float*)(ws + (size_t)NROWS * DIM * 2 + NROWS * 4);   // 128 KB
    float* gstat = (float*)(ws + (size_t)NROWS * DIM * 2 + NROWS * 4 + (size_t)NROWS * 16);

    prep_kernel<<<NROWS / 4, 256, 0, stream>>>(F, Fb, x2, rowacc, gstat);
    pairs_kernel<<<dim3(NT, NT), 256, 0, stream>>>(Fb, x2, labels, rowacc);
    finalize_kernel<<<NROWS / 256, 256, 0, stream>>>(rowacc, gstat);
    div_kernel<<<1, 1, 0, stream>>>(gstat, out);
}

// Round 4
// 125.184 us; speedup vs baseline: 2.6056x; 2.6056x over previous
//
#include <hip/hip_runtime.h>
#include <hip/hip_bf16.h>

// TripletLoss N=8192, D=128. Round 3b: round-1 structure (atomic-free fused
// GEMM+mining j-loop) with a lean epilogue and a parallel tail.
// Key algebra: MFMA C-operand initialized to -(x2i+x2j)/2, so after the
// K-loop acc[r] = dot - (x2i+x2j)/2 = -d2/2. Then
//   s   = v_sqrt(max(-acc, 5e-9))         // dist = sqrt2 * s
//   ne  = exp(-sqrt2 * s) = exp(-dist)    // neg softmax weight
// and all dist-weighted sums are kept in s-units; finalize multiplies by
// sqrt2. Positive pairs (~0.2%) handled in a rare exec-mask branch.

typedef __bf16 bf16x8 __attribute__((ext_vector_type(8)));
typedef float f32x4 __attribute__((ext_vector_type(4)));

#define NROWS 8192
#define DIM 128
#define JTILE 64
#define LDS_STRIDE 136    // 128 + 8 bf16 pad: 272B = 17 x 16B units (odd -> b128 conflict-free)
#define MARGIN_F 0.3f
#define SQRT2_F 1.41421356f

// ---------------- kernel 1: bf16 cast + row norms + zero gstat ----------
__global__ __launch_bounds__(256) void prep_kernel(const float* __restrict__ F,
                                                   __hip_bfloat16* __restrict__ Fb,
                                                   float* __restrict__ x2,
                                                   float* __restrict__ gstat) {
    const int tid = threadIdx.x;
    const int wave = tid >> 6, lane = tid & 63;
    const int row = blockIdx.x * 4 + wave;
    float2 f = ((const float2*)(F + (size_t)row * DIM))[lane];
    ((__hip_bfloat162*)(Fb + (size_t)row * DIM))[lane] = __float22bfloat162_rn(f);
    float ss = f.x * f.x + f.y * f.y;
#pragma unroll
    for (int m = 32; m > 0; m >>= 1) ss += __shfl_xor(ss, m, 64);
    if (lane == 0) x2[row] = ss;
    if (blockIdx.x == 0 && tid < 2) gstat[tid] = 0.f;
}

// ---------------- kernel 2: fused GEMM + mining ----------------
// grid (128, jsplit); block 256 = 4 waves; wave w owns rows rbase..rbase+15,
// iterates over jspan columns in 64-wide LDS tiles. No atomics anywhere.
__global__ __launch_bounds__(256, 6) void pairs_kernel(
        const __hip_bfloat16* __restrict__ Fb,
        const float* __restrict__ x2,
        const int* __restrict__ labels,
        float4* __restrict__ partial,
        int jspan) {
    __shared__ __hip_bfloat16 sB[JTILE * LDS_STRIDE];
    __shared__ int sLab[JTILE];
    __shared__ float sX2h[JTILE];     // -0.5 * x2j

    const int tid = threadIdx.x;
    const int wave = tid >> 6;
    const int lane = tid & 63;
    const int quad = lane >> 4;
    const int lm = lane & 15;
    const int rbase = blockIdx.x * 64 + wave * 16;

    // A fragments (16 rows x K=128) in registers for the whole j loop.
    // A layout: A[m=lane&15][k = quad*8 + j]
    bf16x8 a[4];
#pragma unroll
    for (int kc = 0; kc < 4; ++kc)
        a[kc] = *(const bf16x8*)(Fb + (size_t)(rbase + lm) * DIM + kc * 32 + quad * 8);

    // C/D layout: col(n)=lane&15 (j index), row(m)=quad*4+r (i index)
    int ig[4]; float x2ih[4]; int labi[4];
#pragma unroll
    for (int r = 0; r < 4; ++r) {
        ig[r] = rbase + quad * 4 + r;
        x2ih[r] = -0.5f * x2[ig[r]];
        labi[r] = labels[ig[r]];
    }

    float nl4[4] = {0,0,0,0}, ns4[4] = {0,0,0,0};
    float pl4[4] = {0,0,0,0}, ps4[4] = {0,0,0,0};

    const int j0 = blockIdx.y * jspan;
    const int jiters = jspan / JTILE;

    for (int jb = 0; jb < jiters; ++jb) {
        const int jbase = j0 + jb * JTILE;
        __syncthreads();   // protect LDS from previous iteration's readers
        // stage 64 rows x 256B: 1024 x 16B chunks, 4 per thread, coalesced
#pragma unroll
        for (int s = 0; s < 4; ++s) {
            int c = tid + s * 256;
            int jr = c >> 4, ck = c & 15;
            *(bf16x8*)(sB + jr * LDS_STRIDE + ck * 8) =
                *(const bf16x8*)(Fb + (size_t)(jbase + jr) * DIM + ck * 8);
        }
        if (tid < JTILE) {
            sLab[tid] = labels[jbase + tid];
            sX2h[tid] = -0.5f * x2[jbase + tid];
        }
        __syncthreads();

#pragma unroll
        for (int jt = 0; jt < 4; ++jt) {
            const int jl = jt * 16 + lm;
            const __hip_bfloat16* bp = sB + jl * LDS_STRIDE + quad * 8;
            const float xjh = sX2h[jl];
            f32x4 acc;
#pragma unroll
            for (int r = 0; r < 4; ++r) acc[r] = x2ih[r] + xjh;
#pragma unroll
            for (int kc = 0; kc < 4; ++kc) {
                bf16x8 b = *(const bf16x8*)(bp + kc * 32);
                acc = __builtin_amdgcn_mfma_f32_16x16x32_bf16(a[kc], b, acc, 0, 0, 0);
            }
            const int labj = sLab[jl];
            const int jglob = jbase + jl;
#pragma unroll
            for (int r = 0; r < 4; ++r) {
                // acc[r] = -d2/2; clamp matches reference's clip(d2, 1e-8)
                float d2h = fmaxf(-acc[r], 5e-9f);
                float s = __builtin_amdgcn_sqrtf(d2h);  // dist = sqrt2 * s
                float ne = __expf(-SQRT2_F * s);        // exp(-dist)
                bool same = (labj == labi[r]);
                float mne = same ? 0.f : ne;
                nl4[r] += mne;
                ns4[r] = fmaf(mne, s, ns4[r]);
                if (same && (jglob != ig[r])) {         // rare (~0.2%)
                    float pe = __expf(fmaf(SQRT2_F, s, -30.f));  // exp(dist-30)
                    pl4[r] += pe;
                    ps4[r] = fmaf(pe, s, ps4[r]);
                }
            }
        }
    }

    // reduce over the 16 lanes (lm) sharing each i-row
#pragma unroll
    for (int m = 1; m < 16; m <<= 1) {
#pragma unroll
        for (int r = 0; r < 4; ++r) {
            pl4[r] += __shfl_xor(pl4[r], m, 64);
            ps4[r] += __shfl_xor(ps4[r], m, 64);
            nl4[r] += __shfl_xor(nl4[r], m, 64);
            ns4[r] += __shfl_xor(ns4[r], m, 64);
        }
    }
    if (lm == 0) {
#pragma unroll
        for (int r = 0; r < 4; ++r)
            partial[(size_t)blockIdx.y * NROWS + ig[r]] =
                make_float4(pl4[r], ps4[r], nl4[r], ns4[r]);
    }
}

// ---------------- kernel 3: per-row loss, multi-block reduce -------------
__global__ __launch_bounds__(256) void finalize_kernel(const float4* __restrict__ partial,
                                                       float* __restrict__ gstat,
                                                       int jsplit) {
    const int row = blockIdx.x * 256 + threadIdx.x;
    float pl = 0.f, ps = 0.f, nl = 0.f, ns = 0.f;
    for (int s = 0; s < jsplit; ++s) {
        float4 p = partial[(size_t)s * NROWS + row];
        pl += p.x; ps += p.y; nl += p.z; ns += p.w;
    }
    float sum = 0.f, cnt = 0.f;
    if (pl > 0.f && nl > 0.f) {
        float x = fmaf(SQRT2_F, ps / pl - ns / nl, MARGIN_F);  // wp - wn + margin
        sum = fmaxf(x, 0.f) + log1pf(__expf(-fabsf(x)));       // stable softplus
        cnt = 1.f;
    }
#pragma unroll
    for (int m = 32; m > 0; m >>= 1) {
        sum += __shfl_xor(sum, m, 64);
        cnt += __shfl_xor(cnt, m, 64);
    }
    __shared__ float sS[4], sC[4];
    const int wave = threadIdx.x >> 6, lane = threadIdx.x & 63;
    if (lane == 0) { sS[wave] = sum; sC[wave] = cnt; }
    __syncthreads();
    if (threadIdx.x == 0) {
        unsafeAtomicAdd(&gstat[0], sS[0] + sS[1] + sS[2] + sS[3]);
        unsafeAtomicAdd(&gstat[1], sC[0] + sC[1] + sC[2] + sC[3]);
    }
}

__global__ void div_kernel(const float* __restrict__ gstat, float* __restrict__ out) {
    out[0] = gstat[0] / fmaxf(gstat[1], 1.0f);
}

extern "C" void kernel_launch(void* const* d_in, const int* in_sizes, int n_in,
                              void* d_out, int out_size, void* d_ws, size_t ws_size,
                              hipStream_t stream) {
    const float* F = (const float*)d_in[0];
    const int* labels = (const int*)d_in[1];
    float* out = (float*)d_out;

    char* ws = (char*)d_ws;
    __hip_bfloat16* Fb = (__hip_bfloat16*)ws;                      // 2 MB
    size_t off = (size_t)NROWS * DIM * 2;
    float* x2 = (float*)(ws + off);  off += (size_t)NROWS * 4;     // 32 KB
    float4* partial = (float4*)(ws + off);

    // pick the largest j-split whose partial array fits the workspace
    int jsplit = 16;
    while (jsplit > 1 && off + (size_t)jsplit * NROWS * 16 + 16 > ws_size) jsplit >>= 1;
    float* gstat = (float*)(ws + off + (size_t)jsplit * NROWS * 16);

    prep_kernel<<<NROWS / 4, 256, 0, stream>>>(F, Fb, x2, gstat);
    pairs_kernel<<<dim3(NROWS / 64, jsplit), 256, 0, stream>>>(Fb, x2, labels, partial,
                                                               NROWS / jsplit);
    finalize_kernel<<<NROWS / 256, 256, 0, stream>>>(partial, gstat, jsplit);
    div_kernel<<<1, 1, 0, stream>>>(gstat, out);
}